// Round 12
// baseline (161.364 us; speedup 1.0000x reference)
//
#include <hip/hip_runtime.h>
#include <hip/hip_bf16.h>

#define B_ 8
#define S_ 2048
#define D_ 512

typedef __attribute__((ext_vector_type(8))) short short8;
typedef __attribute__((ext_vector_type(4))) float f32x4;

static __device__ __forceinline__ unsigned short f2bf(float f) {
    union { float f; unsigned u; } v; v.f = f;
    unsigned r = v.u + 0x7FFFu + ((v.u >> 16) & 1u);   // round-nearest-even
    return (unsigned short)(r >> 16);
}

static __device__ __forceinline__ float fexp2(float x) {   // 2^x, native
    float r; asm("v_exp_f32 %0, %1" : "=v"(r) : "v"(x)); return r;
}

static __device__ __forceinline__ void gl_lds16(const void* g, void* l) {
    __builtin_amdgcn_global_load_lds(
        (const __attribute__((address_space(1))) unsigned int*)g,
        (__attribute__((address_space(3))) unsigned int*)l, 16, 0, 0);
}

// ---------------- stage 0: convert x -> bf16, W -> bf16 transposed ----------
__global__ void k_cvt_x(const float* __restrict__ x, unsigned short* __restrict__ xb) {
    int i = blockIdx.x * 256 + threadIdx.x;          // one thread per 8 elems
    const float4* p = (const float4*)x + (size_t)i * 2;
    float4 a = p[0], b = p[1];
    union { unsigned short u[8]; uint4 v; } o;
    o.u[0] = f2bf(a.x); o.u[1] = f2bf(a.y); o.u[2] = f2bf(a.z); o.u[3] = f2bf(a.w);
    o.u[4] = f2bf(b.x); o.u[5] = f2bf(b.y); o.u[6] = f2bf(b.z); o.u[7] = f2bf(b.w);
    ((uint4*)xb)[i] = o.v;
}

// Wt[z][e][d] = bf16(W_z[d][e])
__global__ void k_cvt_w(const float* __restrict__ Wq, const float* __restrict__ Wk,
                        const float* __restrict__ Wv, unsigned short* __restrict__ Wt) {
    int idx = blockIdx.x * 256 + threadIdx.x;        // 0 .. 3*512*512-1
    int z = idx >> 18;
    int r = idx & 262143;
    int e = r >> 9, d = r & 511;
    const float* W = (z == 0) ? Wq : ((z == 1) ? Wk : Wv);
    Wt[idx] = f2bf(W[d * 512 + e]);
}

__global__ void k_lzero(float* __restrict__ l) {
    l[blockIdx.x * 256 + threadIdx.x] = 0.f;
}

// ---------------- stage 1: QKV projection GEMM (dbuf LDS, 1 barrier/step) ---
// z=0 -> Qb [s][d] (pre-scaled log2(e)/sqrt(D)), z=1 -> Kb [s][d],
// z=2 -> Vs tile-major [b][t=s/32][d][s%32]  (= V^T rows, PV B-operand ready).
__global__ __launch_bounds__(256, 4) void k_qkv(
    const unsigned short* __restrict__ xb, const unsigned short* __restrict__ Wt,
    const float* __restrict__ biasq, const float* __restrict__ biask,
    const float* __restrict__ biasv,
    unsigned short* __restrict__ Qb, unsigned short* __restrict__ Kb,
    unsigned short* __restrict__ Vs) {
  __shared__ __align__(16) unsigned char smA[2][16384];  // A [128 m][64 k] swz
  __shared__ __align__(16) unsigned char smB[2][16384];  // B [128 n][64 k] swz
  const int z = blockIdx.z;
  const unsigned short* W = Wt + (size_t)z * (D_ * D_);
  const int lane = threadIdx.x & 63, wid = threadIdx.x >> 6;
  const int c = lane & 15, g = lane >> 4;
  const int wr = wid >> 1, wc = wid & 1;
  const int m_blk = blockIdx.x * 128;
  const int n_blk = blockIdx.y * 128;

  const int src_sw = ((lane & 7) * 16) ^ (((lane >> 3) & 7) << 4);
  const unsigned char* ga = (const unsigned char*)xb
      + (size_t)(m_blk + wid * 32 + (lane >> 3)) * 1024;
  const unsigned char* gb = (const unsigned char*)W
      + (size_t)(n_blk + wid * 32 + (lane >> 3)) * 1024;

#define STAGE1(st_, bp_)                                                     \
  {                                                                          \
    _Pragma("unroll")                                                        \
    for (int i = 0; i < 4; ++i) {                                            \
      gl_lds16(ga + (size_t)i * 8192 + (st_) * 128 + src_sw,                 \
               smA[bp_] + wid * 4096 + i * 1024);                            \
      gl_lds16(gb + (size_t)i * 8192 + (st_) * 128 + src_sw,                 \
               smB[bp_] + wid * 4096 + i * 1024);                            \
    }                                                                        \
  }

  f32x4 acc[4][4];
#pragma unroll
  for (int mi = 0; mi < 4; ++mi)
#pragma unroll
    for (int ni = 0; ni < 4; ++ni) acc[mi][ni] = (f32x4){0.f, 0.f, 0.f, 0.f};

  STAGE1(0, 0);
  __syncthreads();
  for (int step = 0; step < 8; ++step) {
    const int cb = step & 1;
    if (step < 7) STAGE1(step + 1, cb ^ 1);          // hides under compute
#pragma unroll
    for (int kc = 0; kc < 2; ++kc) {
      const int ro = (kc * 64 + g * 16) ^ ((c & 7) << 4);
      short8 af[4], bf[4];
#pragma unroll
      for (int mi = 0; mi < 4; ++mi)
        af[mi] = *(const short8*)(smA[cb] + (wr * 64 + mi * 16 + c) * 128 + ro);
#pragma unroll
      for (int ni = 0; ni < 4; ++ni)
        bf[ni] = *(const short8*)(smB[cb] + (wc * 64 + ni * 16 + c) * 128 + ro);
#pragma unroll
      for (int mi = 0; mi < 4; ++mi)
#pragma unroll
        for (int ni = 0; ni < 4; ++ni)
          acc[mi][ni] = __builtin_amdgcn_mfma_f32_16x16x32_bf16(af[mi], bf[ni], acc[mi][ni], 0, 0, 0);
    }
    __syncthreads();                                 // stage drained; bufs swap
  }
#undef STAGE1

  const int m0 = m_blk + wr * 64;
  const int n0 = n_blk + wc * 64;
  if (z < 2) {
    const float* bias = (z == 0) ? biasq : biask;
    unsigned short* outp = (z == 0) ? Qb : Kb;
    // z=0: log2(e)/sqrt(512) so scores are in exp2 domain
    const float scl = (z == 0) ? 0.0637587238f : 1.0f;
#pragma unroll
    for (int ni = 0; ni < 4; ++ni) {
      int cc = n0 + ni * 16 + c;
      float bb = bias[cc];
#pragma unroll
      for (int mi = 0; mi < 4; ++mi)
#pragma unroll
        for (int r = 0; r < 4; ++r) {
          int row = m0 + mi * 16 + g * 4 + r;
          outp[(size_t)row * D_ + cc] = f2bf((acc[mi][ni][r] + bb) * scl);
        }
    }
  } else {
#pragma unroll
    for (int ni = 0; ni < 4; ++ni) {
      int e = n0 + ni * 16 + c;
      float bb = biasv[e];
#pragma unroll
      for (int mi = 0; mi < 4; ++mi) {
        int row = m0 + mi * 16 + g * 4;       // 4 consecutive s for r=0..3
        int bi = row >> 11, sl = row & 2047;
        int t = sl >> 5, kvin = sl & 31;      // kvin 4-aligned
        union { unsigned short u[4]; uint2 v; } pk;
#pragma unroll
        for (int r = 0; r < 4; ++r) pk.u[r] = f2bf(acc[mi][ni][r] + bb);
        *(uint2*)(Vs + ((((size_t)bi * 64 + t) * 512) + e) * 32 + kvin) = pk.v;
      }
    }
  }
}

// ---------------- stage 2a: P = exp2(S' - 8*log2e), l = row-sums ------------
// SWAPPED operands: C = S^T (m=kv, n=q). 128x128 tile, dbuf LDS,
// 1 barrier/step. Epilogue: bare v_exp_f32 + cvt_pk + uint2 stores.
__global__ __launch_bounds__(256, 4) void k_pa(
    const unsigned short* __restrict__ Qb, const unsigned short* __restrict__ Kb,
    unsigned short* __restrict__ P, float* __restrict__ l,
    int b_base, int bc) {
  __shared__ __align__(16) unsigned char smA[2][16384];
  __shared__ __align__(16) unsigned char smB[2][16384];
  const int lane = threadIdx.x & 63, wid = threadIdx.x >> 6;
  const int c = lane & 15, g = lane >> 4;
  const int wr = wid >> 1, wc = wid & 1;
  const int bloc = blockIdx.x % bc;
  const int tile = blockIdx.x / bc;
  const int b = b_base + bloc;
  const int m_blk = (tile & 15) * 128;      // kv
  const int n_blk = (tile >> 4) * 128;      // q
  unsigned short* Pb = P + (size_t)bloc * S_ * S_;

  const int src_sw = ((lane & 7) * 16) ^ (((lane >> 3) & 7) << 4);
  const unsigned char* ga = (const unsigned char*)(Kb + (size_t)b * S_ * D_)
      + (size_t)(m_blk + wid * 32 + (lane >> 3)) * 1024;   // A = K rows
  const unsigned char* gb = (const unsigned char*)(Qb + (size_t)b * S_ * D_)
      + (size_t)(n_blk + wid * 32 + (lane >> 3)) * 1024;   // B = Q rows

#define STAGE2(st_, bp_)                                                     \
  {                                                                          \
    _Pragma("unroll")                                                        \
    for (int i = 0; i < 4; ++i) {                                            \
      gl_lds16(ga + (size_t)i * 8192 + (st_) * 128 + src_sw,                 \
               smA[bp_] + wid * 4096 + i * 1024);                            \
      gl_lds16(gb + (size_t)i * 8192 + (st_) * 128 + src_sw,                 \
               smB[bp_] + wid * 4096 + i * 1024);                            \
    }                                                                        \
  }

  f32x4 acc[4][4];
#pragma unroll
  for (int mi = 0; mi < 4; ++mi)
#pragma unroll
    for (int ni = 0; ni < 4; ++ni) acc[mi][ni] = (f32x4){0.f, 0.f, 0.f, 0.f};

  STAGE2(0, 0);
  __syncthreads();
  for (int step = 0; step < 8; ++step) {
    const int cb = step & 1;
    if (step < 7) STAGE2(step + 1, cb ^ 1);
#pragma unroll
    for (int kc = 0; kc < 2; ++kc) {
      const int ro = (kc * 64 + g * 16) ^ ((c & 7) << 4);
      short8 af[4], bf[4];
#pragma unroll
      for (int mi = 0; mi < 4; ++mi)
        af[mi] = *(const short8*)(smA[cb] + (wr * 64 + mi * 16 + c) * 128 + ro);
#pragma unroll
      for (int ni = 0; ni < 4; ++ni)
        bf[ni] = *(const short8*)(smB[cb] + (wc * 64 + ni * 16 + c) * 128 + ro);
#pragma unroll
      for (int mi = 0; mi < 4; ++mi)
#pragma unroll
        for (int ni = 0; ni < 4; ++ni)
          acc[mi][ni] = __builtin_amdgcn_mfma_f32_16x16x32_bf16(af[mi], bf[ni], acc[mi][ni], 0, 0, 0);
    }
    __syncthreads();
  }
#undef STAGE2

  const int kv0 = m_blk + wr * 64;          // + mi*16 + g*4 (+r contiguous)
  const int q0  = n_blk + wc * 64;          // + ni*16 + c
  const float SH = 11.5415603f;             // 8*log2(e)
  float psum[4] = {0.f, 0.f, 0.f, 0.f};
#pragma unroll
  for (int ni = 0; ni < 4; ++ni) {
    const int q = q0 + ni * 16 + c;
#pragma unroll
    for (int mi = 0; mi < 4; ++mi) {
      float p0 = fexp2(acc[mi][ni][0] - SH);
      float p1 = fexp2(acc[mi][ni][1] - SH);
      float p2 = fexp2(acc[mi][ni][2] - SH);
      float p3 = fexp2(acc[mi][ni][3] - SH);
      psum[ni] += (p0 + p1) + (p2 + p3);
      unsigned w0, w1;
      asm("v_cvt_pk_bf16_f32 %0, %1, %2" : "=v"(w0) : "v"(p0), "v"(p1));
      asm("v_cvt_pk_bf16_f32 %0, %1, %2" : "=v"(w1) : "v"(p2), "v"(p3));
      *(uint2*)(Pb + (size_t)q * S_ + kv0 + mi * 16 + g * 4) = (uint2){w0, w1};
    }
  }
#pragma unroll
  for (int ni = 0; ni < 4; ++ni) {
    float v = psum[ni];
    v += __shfl_xor(v, 16);
    v += __shfl_xor(v, 32);
    if (g == 0)
      atomicAdd(l + b * S_ + q0 + ni * 16 + c, v);
  }
}

// ---------------- stage 2b: O = (P V) / l, computed as O^T ------------------
// SWAPPED operands: A = Vs (d rows of V^T), B = P (q rows). dbuf LDS,
// 1 barrier/step, 32 steps. 16 float4 stores; m-major tile order for L2.
__global__ __launch_bounds__(256, 4) void k_pb(
    const unsigned short* __restrict__ P, const unsigned short* __restrict__ Vs,
    const float* __restrict__ l, float* __restrict__ out,
    int b_base, int bc) {
  __shared__ __align__(16) unsigned char smA[2][16384];
  __shared__ __align__(16) unsigned char smB[2][16384];
  const int lane = threadIdx.x & 63, wid = threadIdx.x >> 6;
  const int c = lane & 15, g = lane >> 4;
  const int wr = wid >> 1, wc = wid & 1;
  const int bloc = blockIdx.x % bc;
  const int tile = blockIdx.x / bc;         // 0..63
  const int b = b_base + bloc;
  const int m_blk = (tile & 3) * 128;       // d   (m-major: d tiles adjacent)
  const int n_blk = (tile >> 2) * 128;      // q
  const unsigned short* Pb = P + (size_t)bloc * S_ * S_;
  const unsigned char* Vsb = (const unsigned char*)(Vs + (size_t)b * 64 * 512 * 32);

  const int src_sw = ((lane & 7) * 16) ^ (((lane >> 3) & 7) << 4);
  // A = Vs d-rows: 128B LDS row = kv 0..63 = two 32-kv t-halves
  const unsigned char* ga = Vsb + (size_t)(src_sw >> 6) * 32768
      + (size_t)(m_blk + wid * 32 + (lane >> 3)) * 64 + (src_sw & 63);
  // B = P q-rows (row stride 4096B)
  const unsigned char* gb = (const unsigned char*)Pb
      + (size_t)(n_blk + wid * 32 + (lane >> 3)) * 4096;

#define STAGE3(st_, bp_)                                                     \
  {                                                                          \
    _Pragma("unroll")                                                        \
    for (int i = 0; i < 4; ++i) {                                            \
      gl_lds16(ga + (size_t)(st_) * 65536 + i * 512,                         \
               smA[bp_] + wid * 4096 + i * 1024);                            \
      gl_lds16(gb + (size_t)i * 32768 + (st_) * 128 + src_sw,                \
               smB[bp_] + wid * 4096 + i * 1024);                            \
    }                                                                        \
  }

  f32x4 acc[4][4];
#pragma unroll
  for (int mi = 0; mi < 4; ++mi)
#pragma unroll
    for (int ni = 0; ni < 4; ++ni) acc[mi][ni] = (f32x4){0.f, 0.f, 0.f, 0.f};

  STAGE3(0, 0);
  __syncthreads();
  for (int step = 0; step < 32; ++step) {
    const int cb = step & 1;
    if (step < 31) STAGE3(step + 1, cb ^ 1);
#pragma unroll
    for (int kc = 0; kc < 2; ++kc) {
      const int ro = (kc * 64 + g * 16) ^ ((c & 7) << 4);
      short8 af[4], bf[4];
#pragma unroll
      for (int mi = 0; mi < 4; ++mi)
        af[mi] = *(const short8*)(smA[cb] + (wr * 64 + mi * 16 + c) * 128 + ro);
#pragma unroll
      for (int ni = 0; ni < 4; ++ni)
        bf[ni] = *(const short8*)(smB[cb] + (wc * 64 + ni * 16 + c) * 128 + ro);
#pragma unroll
      for (int mi = 0; mi < 4; ++mi)
#pragma unroll
        for (int ni = 0; ni < 4; ++ni)
          acc[mi][ni] = __builtin_amdgcn_mfma_f32_16x16x32_bf16(af[mi], bf[ni], acc[mi][ni], 0, 0, 0);
    }
    __syncthreads();
  }
#undef STAGE3

  const int m0 = m_blk + wr * 64;           // d
  const int n0 = n_blk + wc * 64;           // q
  float* ob = out + (size_t)b * S_ * D_;
#pragma unroll
  for (int ni = 0; ni < 4; ++ni) {
    const int q = n0 + ni * 16 + c;
    const float inv = 1.f / l[b * S_ + q];
#pragma unroll
    for (int mi = 0; mi < 4; ++mi) {
      float4 v;
      v.x = acc[mi][ni][0] * inv; v.y = acc[mi][ni][1] * inv;
      v.z = acc[mi][ni][2] * inv; v.w = acc[mi][ni][3] * inv;
      *(float4*)(ob + (size_t)q * D_ + m0 + mi * 16 + g * 4) = v;
    }
  }
}

// ---------------- launch ----------------------------------------------------
extern "C" void kernel_launch(void* const* d_in, const int* in_sizes, int n_in,
                              void* d_out, int out_size, void* d_ws, size_t ws_size,
                              hipStream_t stream) {
  const float* x  = (const float*)d_in[0];
  const float* Wq = (const float*)d_in[1];
  const float* bq = (const float*)d_in[2];
  const float* Wk = (const float*)d_in[3];
  const float* bk = (const float*)d_in[4];
  const float* Wv = (const float*)d_in[5];
  const float* bv = (const float*)d_in[6];
  float* out = (float*)d_out;

  // workspace layout (bf16)
  unsigned short* xb = (unsigned short*)d_ws;              // [16384][512]  (dead after k_qkv)
  unsigned short* Wt = xb + (size_t)16384 * 512;           // [3][512][512] (dead after k_qkv)
  unsigned short* Qb = Wt + (size_t)3 * 512 * 512;         // [16384][512], pre-scaled
  unsigned short* Kb = Qb + (size_t)16384 * 512;           // [16384][512]
  unsigned short* Vs = Kb + (size_t)16384 * 512;           // [8][64][512][32] tile-major
  float* l = (float*)Wt;                                   // [8][2048] f32, reuses Wt
  unsigned short* Pfull = Vs + (size_t)8 * 64 * 512 * 32;  // [8][2048][2048] (if ws allows)
  const size_t full_need =
      (size_t)((unsigned char*)(Pfull + (size_t)8 * 2048 * 2048) - (unsigned char*)d_ws);

  k_cvt_x<<<dim3(4096), dim3(256), 0, stream>>>(x, xb);
  k_cvt_w<<<dim3(3072), dim3(256), 0, stream>>>(Wq, Wk, Wv, Wt);
  k_qkv<<<dim3(128, 4, 3), dim3(256), 0, stream>>>(xb, Wt, bq, bk, bv, Qb, Kb, Vs);
  k_lzero<<<dim3(64), dim3(256), 0, stream>>>(l);

  if (ws_size >= full_need) {
    k_pa<<<dim3(2048), dim3(256), 0, stream>>>(Qb, Kb, Pfull, l, 0, 8);
    k_pb<<<dim3(512),  dim3(256), 0, stream>>>(Pfull, Vs, l, out, 0, 8);
  } else {
    // 2 batches of P fit exactly in the dead xb region (16.7 MB).
    unsigned short* P2 = xb;
    for (int g2 = 0; g2 < 4; ++g2) {
      k_pa<<<dim3(512), dim3(256), 0, stream>>>(Qb, Kb, P2, l, g2 * 2, 2);
      k_pb<<<dim3(128), dim3(256), 0, stream>>>(P2, Vs, l, out, g2 * 2, 2);
    }
  }
}

// Round 14
// 139.471 us; speedup vs baseline: 1.1570x; 1.1570x over previous
//
#include <hip/hip_runtime.h>
#include <hip/hip_bf16.h>

#define B_ 8
#define S_ 2048
#define D_ 512

typedef __attribute__((ext_vector_type(8))) short short8;
typedef __attribute__((ext_vector_type(4))) float f32x4;

static __device__ __forceinline__ unsigned short f2bf(float f) {
    union { float f; unsigned u; } v; v.f = f;
    unsigned r = v.u + 0x7FFFu + ((v.u >> 16) & 1u);   // round-nearest-even
    return (unsigned short)(r >> 16);
}

static __device__ __forceinline__ float fexp2(float x) {   // 2^x, native
    float r; asm("v_exp_f32 %0, %1" : "=v"(r) : "v"(x)); return r;
}

static __device__ __forceinline__ void gl_lds16(const void* g, void* l) {
    __builtin_amdgcn_global_load_lds(
        (const __attribute__((address_space(1))) unsigned int*)g,
        (__attribute__((address_space(3))) unsigned int*)l, 16, 0, 0);
}

// ---------------- stage 0 (fused): x->bf16, W->bf16^T, l=0 ------------------
// blocks [0,4096): x cvt; [4096,7168): W cvt; [7168,7232): l zero.
// NOTE: l has its OWN workspace slot (aliasing l onto Wt raced in-kernel).
__global__ void k_prep(const float* __restrict__ x,
                       const float* __restrict__ Wq, const float* __restrict__ Wk,
                       const float* __restrict__ Wv,
                       unsigned short* __restrict__ xb, unsigned short* __restrict__ Wt,
                       float* __restrict__ l) {
    int bid = blockIdx.x;
    if (bid < 4096) {
        int i = bid * 256 + threadIdx.x;             // one thread per 8 elems
        const float4* p = (const float4*)x + (size_t)i * 2;
        float4 a = p[0], b = p[1];
        union { unsigned short u[8]; uint4 v; } o;
        o.u[0] = f2bf(a.x); o.u[1] = f2bf(a.y); o.u[2] = f2bf(a.z); o.u[3] = f2bf(a.w);
        o.u[4] = f2bf(b.x); o.u[5] = f2bf(b.y); o.u[6] = f2bf(b.z); o.u[7] = f2bf(b.w);
        ((uint4*)xb)[i] = o.v;
    } else if (bid < 7168) {
        int idx = (bid - 4096) * 256 + threadIdx.x;  // 0 .. 3*512*512-1
        int z = idx >> 18;
        int r = idx & 262143;
        int e = r >> 9, d = r & 511;
        const float* W = (z == 0) ? Wq : ((z == 1) ? Wk : Wv);
        Wt[idx] = f2bf(W[d * 512 + e]);
    } else {
        l[(bid - 7168) * 256 + threadIdx.x] = 0.f;
    }
}

// ---------------- stage 1: QKV projection GEMM (LDS-staged, 128x128) --------
// z=0 -> Qb [s][d] (pre-scaled log2(e)/sqrt(D)), z=1 -> Kb [s][d],
// z=2 -> Vs tile-major [b][t=s/32][d][s%32]  (= V^T rows, PV B-operand ready).
__global__ __launch_bounds__(256, 4) void k_qkv(
    const unsigned short* __restrict__ xb, const unsigned short* __restrict__ Wt,
    const float* __restrict__ biasq, const float* __restrict__ biask,
    const float* __restrict__ biasv,
    unsigned short* __restrict__ Qb, unsigned short* __restrict__ Kb,
    unsigned short* __restrict__ Vs) {
  __shared__ __align__(16) unsigned char smA[16384];   // A tile [128 m][64 k], swz
  __shared__ __align__(16) unsigned char smB[16384];   // B tile [128 n][64 k], swz
  const int z = blockIdx.z;
  const unsigned short* W = Wt + (size_t)z * (D_ * D_);
  const int lane = threadIdx.x & 63, wid = threadIdx.x >> 6;
  const int c = lane & 15, g = lane >> 4;
  const int wr = wid >> 1, wc = wid & 1;
  const int m_blk = blockIdx.x * 128;
  const int n_blk = blockIdx.y * 128;

  const int src_sw = ((lane & 7) * 16) ^ (((lane >> 3) & 7) << 4);
  const unsigned char* ga = (const unsigned char*)xb
      + (size_t)(m_blk + wid * 32 + (lane >> 3)) * 1024;
  const unsigned char* gb = (const unsigned char*)W
      + (size_t)(n_blk + wid * 32 + (lane >> 3)) * 1024;
  unsigned char* la = smA + wid * 4096;
  unsigned char* lb = smB + wid * 4096;

  f32x4 acc[4][4];
#pragma unroll
  for (int mi = 0; mi < 4; ++mi)
#pragma unroll
    for (int ni = 0; ni < 4; ++ni) acc[mi][ni] = (f32x4){0.f, 0.f, 0.f, 0.f};

  for (int step = 0; step < 8; ++step) {
    __syncthreads();                                  // prev-tile reads done
#pragma unroll
    for (int i = 0; i < 4; ++i) {
      gl_lds16(ga + (size_t)i * 8192 + step * 128 + src_sw, la + i * 1024);
      gl_lds16(gb + (size_t)i * 8192 + step * 128 + src_sw, lb + i * 1024);
    }
    __syncthreads();                                  // staged data visible
#pragma unroll
    for (int kc = 0; kc < 2; ++kc) {
      const int ro = (kc * 64 + g * 16) ^ ((c & 7) << 4);
      short8 af[4], bf[4];
#pragma unroll
      for (int mi = 0; mi < 4; ++mi)
        af[mi] = *(const short8*)(smA + (wr * 64 + mi * 16 + c) * 128 + ro);
#pragma unroll
      for (int ni = 0; ni < 4; ++ni)
        bf[ni] = *(const short8*)(smB + (wc * 64 + ni * 16 + c) * 128 + ro);
#pragma unroll
      for (int mi = 0; mi < 4; ++mi)
#pragma unroll
        for (int ni = 0; ni < 4; ++ni)
          acc[mi][ni] = __builtin_amdgcn_mfma_f32_16x16x32_bf16(af[mi], bf[ni], acc[mi][ni], 0, 0, 0);
    }
  }

  const int m0 = m_blk + wr * 64;
  const int n0 = n_blk + wc * 64;
  if (z < 2) {
    const float* bias = (z == 0) ? biasq : biask;
    unsigned short* outp = (z == 0) ? Qb : Kb;
    // z=0: log2(e)/sqrt(512) so scores are in exp2 domain
    const float scl = (z == 0) ? 0.0637587238f : 1.0f;
#pragma unroll
    for (int ni = 0; ni < 4; ++ni) {
      int cc = n0 + ni * 16 + c;
      float bb = bias[cc];
#pragma unroll
      for (int mi = 0; mi < 4; ++mi)
#pragma unroll
        for (int r = 0; r < 4; ++r) {
          int row = m0 + mi * 16 + g * 4 + r;
          outp[(size_t)row * D_ + cc] = f2bf((acc[mi][ni][r] + bb) * scl);
        }
    }
  } else {
#pragma unroll
    for (int ni = 0; ni < 4; ++ni) {
      int e = n0 + ni * 16 + c;
      float bb = biasv[e];
#pragma unroll
      for (int mi = 0; mi < 4; ++mi) {
        int row = m0 + mi * 16 + g * 4;       // 4 consecutive s for r=0..3
        int bi = row >> 11, sl = row & 2047;
        int t = sl >> 5, kvin = sl & 31;      // kvin 4-aligned
        union { unsigned short u[4]; uint2 v; } pk;
#pragma unroll
        for (int r = 0; r < 4; ++r) pk.u[r] = f2bf(acc[mi][ni][r] + bb);
        *(uint2*)(Vs + ((((size_t)bi * 64 + t) * 512) + e) * 32 + kvin) = pk.v;
      }
    }
  }
}

// ---------------- stage 2a: P = exp2(S' - 8*log2e), l = row-sums ------------
// SWAPPED operands: C = S^T (m=kv, n=q). 128x128, single-buffer 2-barrier
// (proven register-optimal: 64 VGPR + 64 AGPR = 4 waves/SIMD).
__global__ __launch_bounds__(256, 4) void k_pa(
    const unsigned short* __restrict__ Qb, const unsigned short* __restrict__ Kb,
    unsigned short* __restrict__ P, float* __restrict__ l,
    int b_base, int bc) {
  __shared__ __align__(16) unsigned char smA[16384];
  __shared__ __align__(16) unsigned char smB[16384];
  const int lane = threadIdx.x & 63, wid = threadIdx.x >> 6;
  const int c = lane & 15, g = lane >> 4;
  const int wr = wid >> 1, wc = wid & 1;
  const int bloc = blockIdx.x % bc;
  const int tile = blockIdx.x / bc;
  const int b = b_base + bloc;
  const int m_blk = (tile & 15) * 128;      // kv
  const int n_blk = (tile >> 4) * 128;      // q
  unsigned short* Pb = P + (size_t)bloc * S_ * S_;

  const int src_sw = ((lane & 7) * 16) ^ (((lane >> 3) & 7) << 4);
  const unsigned char* ga = (const unsigned char*)(Kb + (size_t)b * S_ * D_)
      + (size_t)(m_blk + wid * 32 + (lane >> 3)) * 1024;   // A = K rows
  const unsigned char* gb = (const unsigned char*)(Qb + (size_t)b * S_ * D_)
      + (size_t)(n_blk + wid * 32 + (lane >> 3)) * 1024;   // B = Q rows
  unsigned char* la = smA + wid * 4096;
  unsigned char* lb = smB + wid * 4096;

  f32x4 acc[4][4];
#pragma unroll
  for (int mi = 0; mi < 4; ++mi)
#pragma unroll
    for (int ni = 0; ni < 4; ++ni) acc[mi][ni] = (f32x4){0.f, 0.f, 0.f, 0.f};

  for (int step = 0; step < 8; ++step) {
    __syncthreads();
#pragma unroll
    for (int i = 0; i < 4; ++i) {
      gl_lds16(ga + (size_t)i * 8192 + step * 128 + src_sw, la + i * 1024);
      gl_lds16(gb + (size_t)i * 8192 + step * 128 + src_sw, lb + i * 1024);
    }
    __syncthreads();
#pragma unroll
    for (int kc = 0; kc < 2; ++kc) {
      const int ro = (kc * 64 + g * 16) ^ ((c & 7) << 4);
      short8 af[4], bf[4];
#pragma unroll
      for (int mi = 0; mi < 4; ++mi)
        af[mi] = *(const short8*)(smA + (wr * 64 + mi * 16 + c) * 128 + ro);
#pragma unroll
      for (int ni = 0; ni < 4; ++ni)
        bf[ni] = *(const short8*)(smB + (wc * 64 + ni * 16 + c) * 128 + ro);
#pragma unroll
      for (int mi = 0; mi < 4; ++mi)
#pragma unroll
        for (int ni = 0; ni < 4; ++ni)
          acc[mi][ni] = __builtin_amdgcn_mfma_f32_16x16x32_bf16(af[mi], bf[ni], acc[mi][ni], 0, 0, 0);
    }
  }

  const int kv0 = m_blk + wr * 64;          // + mi*16 + g*4 (+r contiguous)
  const int q0  = n_blk + wc * 64;          // + ni*16 + c
  const float SH = 11.5415603f;             // 8*log2(e)
  float psum[4] = {0.f, 0.f, 0.f, 0.f};
#pragma unroll
  for (int ni = 0; ni < 4; ++ni) {
    const int q = q0 + ni * 16 + c;
#pragma unroll
    for (int mi = 0; mi < 4; ++mi) {
      float p0 = fexp2(acc[mi][ni][0] - SH);
      float p1 = fexp2(acc[mi][ni][1] - SH);
      float p2 = fexp2(acc[mi][ni][2] - SH);
      float p3 = fexp2(acc[mi][ni][3] - SH);
      psum[ni] += (p0 + p1) + (p2 + p3);
      unsigned w0, w1;
      asm("v_cvt_pk_bf16_f32 %0, %1, %2" : "=v"(w0) : "v"(p0), "v"(p1));
      asm("v_cvt_pk_bf16_f32 %0, %1, %2" : "=v"(w1) : "v"(p2), "v"(p3));
      *(uint2*)(Pb + (size_t)q * S_ + kv0 + mi * 16 + g * 4) = (uint2){w0, w1};
    }
  }
#pragma unroll
  for (int ni = 0; ni < 4; ++ni) {
    float v = psum[ni];
    v += __shfl_xor(v, 16);
    v += __shfl_xor(v, 32);
    if (g == 0)
      atomicAdd(l + b * S_ + q0 + ni * 16 + c, v);
  }
}

// ---------------- stage 2b: O = (P V) / l, computed as O^T ------------------
// SWAPPED operands: A = Vs (d rows of V^T), B = P (q rows). 256d x 128q tile,
// 8 waves (wave = 64d x 64q, acc/regs unchanged). Halves P L3 amplification
// (2 d-tiles instead of 4). grid 32/batch; d-major pairs share the P q-panel.
__global__ __launch_bounds__(512, 2) void k_pb(
    const unsigned short* __restrict__ P, const unsigned short* __restrict__ Vs,
    const float* __restrict__ l, float* __restrict__ out,
    int b_base, int bc) {
  __shared__ __align__(16) unsigned char smA[32768];   // Vs 256 d-rows x 128B
  __shared__ __align__(16) unsigned char smB[16384];   // P  128 q-rows x 128B
  const int lane = threadIdx.x & 63, wid = threadIdx.x >> 6;  // wid 0..7
  const int c = lane & 15, g = lane >> 4;
  const int wr = wid >> 1, wc = wid & 1;    // wr 0..3 (d), wc 0..1 (q)
  const int bloc = blockIdx.x % bc;
  const int tile = blockIdx.x / bc;         // 0..31
  const int b = b_base + bloc;
  const int m_blk = (tile & 1) * 256;       // d   (d-major: d-pair adjacent)
  const int n_blk = (tile >> 1) * 128;      // q
  const unsigned short* Pb = P + (size_t)bloc * S_ * S_;
  const unsigned char* Vsb = (const unsigned char*)(Vs + (size_t)b * 64 * 512 * 32);

  const int src_sw = ((lane & 7) * 16) ^ (((lane >> 3) & 7) << 4);
  // A = Vs d-rows: 128B LDS row = kv 0..63 = two 32-kv t-halves.
  // wave stages rows wid*32 .. +31 (4 gl_lds of 8 rows each)
  const unsigned char* ga = Vsb + (size_t)(src_sw >> 6) * 32768
      + (size_t)(m_blk + wid * 32 + (lane >> 3)) * 64 + (src_sw & 63);
  // B = P q-rows (row stride 4096B); wave stages rows wid*16 .. +15 (2 gl_lds)
  const unsigned char* gb = (const unsigned char*)Pb
      + (size_t)(n_blk + wid * 16 + (lane >> 3)) * 4096;
  unsigned char* la = smA + wid * 4096;     // 32 rows x 128B
  unsigned char* lb = smB + wid * 2048;     // 16 rows x 128B

  f32x4 acc[4][4];
#pragma unroll
  for (int mi = 0; mi < 4; ++mi)
#pragma unroll
    for (int ni = 0; ni < 4; ++ni) acc[mi][ni] = (f32x4){0.f, 0.f, 0.f, 0.f};

  for (int step = 0; step < 32; ++step) {
    __syncthreads();
#pragma unroll
    for (int i = 0; i < 4; ++i)
      gl_lds16(ga + (size_t)step * 65536 + i * 512, la + i * 1024);
#pragma unroll
    for (int i = 0; i < 2; ++i)
      gl_lds16(gb + (size_t)i * 32768 + step * 128 + src_sw, lb + i * 1024);
    __syncthreads();
#pragma unroll
    for (int kc = 0; kc < 2; ++kc) {
      const int ro = (kc * 64 + g * 16) ^ ((c & 7) << 4);
      short8 af[4], bf[4];
#pragma unroll
      for (int mi = 0; mi < 4; ++mi)
        af[mi] = *(const short8*)(smA + (wr * 64 + mi * 16 + c) * 128 + ro);
#pragma unroll
      for (int ni = 0; ni < 4; ++ni)
        bf[ni] = *(const short8*)(smB + (wc * 64 + ni * 16 + c) * 128 + ro);
#pragma unroll
      for (int mi = 0; mi < 4; ++mi)
#pragma unroll
        for (int ni = 0; ni < 4; ++ni)
          acc[mi][ni] = __builtin_amdgcn_mfma_f32_16x16x32_bf16(af[mi], bf[ni], acc[mi][ni], 0, 0, 0);
    }
  }

  const int m0 = m_blk + wr * 64;           // d
  const int n0 = n_blk + wc * 64;           // q
  float* ob = out + (size_t)b * S_ * D_;
#pragma unroll
  for (int ni = 0; ni < 4; ++ni) {
    const int q = n0 + ni * 16 + c;
    const float inv = 1.f / l[b * S_ + q];
#pragma unroll
    for (int mi = 0; mi < 4; ++mi) {
      float4 v;
      v.x = acc[mi][ni][0] * inv; v.y = acc[mi][ni][1] * inv;
      v.z = acc[mi][ni][2] * inv; v.w = acc[mi][ni][3] * inv;
      *(float4*)(ob + (size_t)q * D_ + m0 + mi * 16 + g * 4) = v;
    }
  }
}

// ---------------- launch ----------------------------------------------------
extern "C" void kernel_launch(void* const* d_in, const int* in_sizes, int n_in,
                              void* d_out, int out_size, void* d_ws, size_t ws_size,
                              hipStream_t stream) {
  const float* x  = (const float*)d_in[0];
  const float* Wq = (const float*)d_in[1];
  const float* bq = (const float*)d_in[2];
  const float* Wk = (const float*)d_in[3];
  const float* bk = (const float*)d_in[4];
  const float* Wv = (const float*)d_in[5];
  const float* bv = (const float*)d_in[6];
  float* out = (float*)d_out;

  // workspace layout (bf16 unless noted)
  unsigned short* xb = (unsigned short*)d_ws;              // [16384][512]  (dead after k_qkv)
  unsigned short* Wt = xb + (size_t)16384 * 512;           // [3][512][512] (dead after k_qkv)
  unsigned short* Qb = Wt + (size_t)3 * 512 * 512;         // [16384][512], pre-scaled
  unsigned short* Kb = Qb + (size_t)16384 * 512;           // [16384][512]
  unsigned short* Vs = Kb + (size_t)16384 * 512;           // [8][64][512][32] tile-major
  float* l = (float*)(Vs + (size_t)8 * 64 * 512 * 32);     // [8][2048] f32 — OWN slot
  unsigned short* Pfull = (unsigned short*)(l + 8 * 2048); // [8][2048][2048] (if ws allows)
  const size_t full_need =
      (size_t)((unsigned char*)(Pfull + (size_t)8 * 2048 * 2048) - (unsigned char*)d_ws);
  const size_t part_need =
      (size_t)((unsigned char*)(l + 8 * 2048) - (unsigned char*)d_ws);
  (void)part_need;

  k_prep<<<dim3(7232), dim3(256), 0, stream>>>(x, Wq, Wk, Wv, xb, Wt, l);
  k_qkv<<<dim3(128, 4, 3), dim3(256), 0, stream>>>(xb, Wt, bq, bk, bv, Qb, Kb, Vs);

  if (ws_size >= full_need) {
    k_pa<<<dim3(2048), dim3(256), 0, stream>>>(Qb, Kb, Pfull, l, 0, 8);
    k_pb<<<dim3(256),  dim3(512), 0, stream>>>(Pfull, Vs, l, out, 0, 8);
  } else {
    // 2 batches of P fit exactly in the dead xb region (16.7 MB).
    unsigned short* P2 = xb;
    for (int g2 = 0; g2 < 4; ++g2) {
      k_pa<<<dim3(512), dim3(256), 0, stream>>>(Qb, Kb, P2, l, g2 * 2, 2);
      k_pb<<<dim3(64), dim3(512), 0, stream>>>(P2, Vs, l, out, g2 * 2, 2);
    }
  }
}

// Round 15
// 123.494 us; speedup vs baseline: 1.3067x; 1.1294x over previous
//
#include <hip/hip_runtime.h>
#include <hip/hip_bf16.h>

#define B_ 8
#define S_ 2048
#define D_ 512

typedef __attribute__((ext_vector_type(8))) short short8;
typedef __attribute__((ext_vector_type(4))) float f32x4;

static __device__ __forceinline__ unsigned short f2bf(float f) {
    union { float f; unsigned u; } v; v.f = f;
    unsigned r = v.u + 0x7FFFu + ((v.u >> 16) & 1u);   // round-nearest-even
    return (unsigned short)(r >> 16);
}

static __device__ __forceinline__ float fexp2(float x) {   // 2^x, native
    float r; asm("v_exp_f32 %0, %1" : "=v"(r) : "v"(x)); return r;
}

static __device__ __forceinline__ void gl_lds16(const void* g, void* l) {
    __builtin_amdgcn_global_load_lds(
        (const __attribute__((address_space(1))) unsigned int*)g,
        (__attribute__((address_space(3))) unsigned int*)l, 16, 0, 0);
}

// ---------------- stage 0 (fused): x->bf16, W->bf16^T, l=0 ------------------
// blocks [0,4096): x cvt; [4096,7168): W cvt; [7168,7232): l zero.
// NOTE: l has its OWN workspace slot (aliasing l onto Wt raced in-kernel).
__global__ void k_prep(const float* __restrict__ x,
                       const float* __restrict__ Wq, const float* __restrict__ Wk,
                       const float* __restrict__ Wv,
                       unsigned short* __restrict__ xb, unsigned short* __restrict__ Wt,
                       float* __restrict__ l) {
    int bid = blockIdx.x;
    if (bid < 4096) {
        int i = bid * 256 + threadIdx.x;             // one thread per 8 elems
        const float4* p = (const float4*)x + (size_t)i * 2;
        float4 a = p[0], b = p[1];
        union { unsigned short u[8]; uint4 v; } o;
        o.u[0] = f2bf(a.x); o.u[1] = f2bf(a.y); o.u[2] = f2bf(a.z); o.u[3] = f2bf(a.w);
        o.u[4] = f2bf(b.x); o.u[5] = f2bf(b.y); o.u[6] = f2bf(b.z); o.u[7] = f2bf(b.w);
        ((uint4*)xb)[i] = o.v;
    } else if (bid < 7168) {
        int idx = (bid - 4096) * 256 + threadIdx.x;  // 0 .. 3*512*512-1
        int z = idx >> 18;
        int r = idx & 262143;
        int e = r >> 9, d = r & 511;
        const float* W = (z == 0) ? Wq : ((z == 1) ? Wk : Wv);
        Wt[idx] = f2bf(W[d * 512 + e]);
    } else {
        l[(bid - 7168) * 256 + threadIdx.x] = 0.f;
    }
}

// ---------------- stage 1: QKV projection GEMM (LDS-staged, 128x128) --------
// z=0 -> Qb [s][d] (pre-scaled log2(e)/sqrt(D)), z=1 -> Kb [s][d],
// z=2 -> Vs tile-major [b][t=s/32][d][s%32]  (= V^T rows, PV B-operand ready).
__global__ __launch_bounds__(256, 4) void k_qkv(
    const unsigned short* __restrict__ xb, const unsigned short* __restrict__ Wt,
    const float* __restrict__ biasq, const float* __restrict__ biask,
    const float* __restrict__ biasv,
    unsigned short* __restrict__ Qb, unsigned short* __restrict__ Kb,
    unsigned short* __restrict__ Vs) {
  __shared__ __align__(16) unsigned char smA[16384];   // A tile [128 m][64 k], swz
  __shared__ __align__(16) unsigned char smB[16384];   // B tile [128 n][64 k], swz
  const int z = blockIdx.z;
  const unsigned short* W = Wt + (size_t)z * (D_ * D_);
  const int lane = threadIdx.x & 63, wid = threadIdx.x >> 6;
  const int c = lane & 15, g = lane >> 4;
  const int wr = wid >> 1, wc = wid & 1;
  const int m_blk = blockIdx.x * 128;
  const int n_blk = blockIdx.y * 128;

  const int src_sw = ((lane & 7) * 16) ^ (((lane >> 3) & 7) << 4);
  const unsigned char* ga = (const unsigned char*)xb
      + (size_t)(m_blk + wid * 32 + (lane >> 3)) * 1024;
  const unsigned char* gb = (const unsigned char*)W
      + (size_t)(n_blk + wid * 32 + (lane >> 3)) * 1024;
  unsigned char* la = smA + wid * 4096;
  unsigned char* lb = smB + wid * 4096;

  f32x4 acc[4][4];
#pragma unroll
  for (int mi = 0; mi < 4; ++mi)
#pragma unroll
    for (int ni = 0; ni < 4; ++ni) acc[mi][ni] = (f32x4){0.f, 0.f, 0.f, 0.f};

  for (int step = 0; step < 8; ++step) {
    __syncthreads();                                  // prev-tile reads done
#pragma unroll
    for (int i = 0; i < 4; ++i) {
      gl_lds16(ga + (size_t)i * 8192 + step * 128 + src_sw, la + i * 1024);
      gl_lds16(gb + (size_t)i * 8192 + step * 128 + src_sw, lb + i * 1024);
    }
    __syncthreads();                                  // staged data visible
#pragma unroll
    for (int kc = 0; kc < 2; ++kc) {
      const int ro = (kc * 64 + g * 16) ^ ((c & 7) << 4);
      short8 af[4], bf[4];
#pragma unroll
      for (int mi = 0; mi < 4; ++mi)
        af[mi] = *(const short8*)(smA + (wr * 64 + mi * 16 + c) * 128 + ro);
#pragma unroll
      for (int ni = 0; ni < 4; ++ni)
        bf[ni] = *(const short8*)(smB + (wc * 64 + ni * 16 + c) * 128 + ro);
#pragma unroll
      for (int mi = 0; mi < 4; ++mi)
#pragma unroll
        for (int ni = 0; ni < 4; ++ni)
          acc[mi][ni] = __builtin_amdgcn_mfma_f32_16x16x32_bf16(af[mi], bf[ni], acc[mi][ni], 0, 0, 0);
    }
  }

  const int m0 = m_blk + wr * 64;
  const int n0 = n_blk + wc * 64;
  if (z < 2) {
    const float* bias = (z == 0) ? biasq : biask;
    unsigned short* outp = (z == 0) ? Qb : Kb;
    // z=0: log2(e)/sqrt(512) so scores are in exp2 domain
    const float scl = (z == 0) ? 0.0637587238f : 1.0f;
#pragma unroll
    for (int ni = 0; ni < 4; ++ni) {
      int cc = n0 + ni * 16 + c;
      float bb = bias[cc];
#pragma unroll
      for (int mi = 0; mi < 4; ++mi)
#pragma unroll
        for (int r = 0; r < 4; ++r) {
          int row = m0 + mi * 16 + g * 4 + r;
          outp[(size_t)row * D_ + cc] = f2bf((acc[mi][ni][r] + bb) * scl);
        }
    }
  } else {
#pragma unroll
    for (int ni = 0; ni < 4; ++ni) {
      int e = n0 + ni * 16 + c;
      float bb = biasv[e];
#pragma unroll
      for (int mi = 0; mi < 4; ++mi) {
        int row = m0 + mi * 16 + g * 4;       // 4 consecutive s for r=0..3
        int bi = row >> 11, sl = row & 2047;
        int t = sl >> 5, kvin = sl & 31;      // kvin 4-aligned
        union { unsigned short u[4]; uint2 v; } pk;
#pragma unroll
        for (int r = 0; r < 4; ++r) pk.u[r] = f2bf(acc[mi][ni][r] + bb);
        *(uint2*)(Vs + ((((size_t)bi * 64 + t) * 512) + e) * 32 + kvin) = pk.v;
      }
    }
  }
}

// ---------------- stage 2a: P = exp2(S' - 8*log2e), l = row-sums ------------
// SWAPPED operands: C = S^T (m=kv, n=q). 128x128, single-buffer 2-barrier
// (register-optimal: 64 VGPR + 64 AGPR = 4 blocks/CU). NEW: epilogue packs
// the bf16 P tile through LDS (XOR-swizzled) so global stores are 8 coalesced
// uint4 (4 rows x 256B per instr) instead of 16 x 64-line scatters.
__global__ __launch_bounds__(256, 4) void k_pa(
    const unsigned short* __restrict__ Qb, const unsigned short* __restrict__ Kb,
    unsigned short* __restrict__ P, float* __restrict__ l,
    int b_base, int bc) {
  __shared__ __align__(16) unsigned char smA[16384];
  __shared__ __align__(16) unsigned char smB[16384];
  const int lane = threadIdx.x & 63, wid = threadIdx.x >> 6;
  const int c = lane & 15, g = lane >> 4;
  const int wr = wid >> 1, wc = wid & 1;
  const int bloc = blockIdx.x % bc;
  const int tile = blockIdx.x / bc;
  const int b = b_base + bloc;
  const int m_blk = (tile & 15) * 128;      // kv
  const int n_blk = (tile >> 4) * 128;      // q
  unsigned short* Pb = P + (size_t)bloc * S_ * S_;

  const int src_sw = ((lane & 7) * 16) ^ (((lane >> 3) & 7) << 4);
  const unsigned char* ga = (const unsigned char*)(Kb + (size_t)b * S_ * D_)
      + (size_t)(m_blk + wid * 32 + (lane >> 3)) * 1024;   // A = K rows
  const unsigned char* gb = (const unsigned char*)(Qb + (size_t)b * S_ * D_)
      + (size_t)(n_blk + wid * 32 + (lane >> 3)) * 1024;   // B = Q rows
  unsigned char* la = smA + wid * 4096;
  unsigned char* lb = smB + wid * 4096;

  f32x4 acc[4][4];
#pragma unroll
  for (int mi = 0; mi < 4; ++mi)
#pragma unroll
    for (int ni = 0; ni < 4; ++ni) acc[mi][ni] = (f32x4){0.f, 0.f, 0.f, 0.f};

  for (int step = 0; step < 8; ++step) {
    __syncthreads();
#pragma unroll
    for (int i = 0; i < 4; ++i) {
      gl_lds16(ga + (size_t)i * 8192 + step * 128 + src_sw, la + i * 1024);
      gl_lds16(gb + (size_t)i * 8192 + step * 128 + src_sw, lb + i * 1024);
    }
    __syncthreads();
#pragma unroll
    for (int kc = 0; kc < 2; ++kc) {
      const int ro = (kc * 64 + g * 16) ^ ((c & 7) << 4);
      short8 af[4], bf[4];
#pragma unroll
      for (int mi = 0; mi < 4; ++mi)
        af[mi] = *(const short8*)(smA + (wr * 64 + mi * 16 + c) * 128 + ro);
#pragma unroll
      for (int ni = 0; ni < 4; ++ni)
        bf[ni] = *(const short8*)(smB + (wc * 64 + ni * 16 + c) * 128 + ro);
#pragma unroll
      for (int mi = 0; mi < 4; ++mi)
#pragma unroll
        for (int ni = 0; ni < 4; ++ni)
          acc[mi][ni] = __builtin_amdgcn_mfma_f32_16x16x32_bf16(af[mi], bf[ni], acc[mi][ni], 0, 0, 0);
    }
  }

  const float SH = 11.5415603f;             // 8*log2(e)
  float psum[4] = {0.f, 0.f, 0.f, 0.f};
  __syncthreads();                          // K-loop LDS reads done; smA free
  // pack tile into smA: [q_loc 0..127][256B kv], byte = q*256 + (kv2 ^ ((q&15)<<4))
#pragma unroll
  for (int ni = 0; ni < 4; ++ni) {
    const int q_loc = wc * 64 + ni * 16 + c;
#pragma unroll
    for (int mi = 0; mi < 4; ++mi) {
      float p0 = fexp2(acc[mi][ni][0] - SH);
      float p1 = fexp2(acc[mi][ni][1] - SH);
      float p2 = fexp2(acc[mi][ni][2] - SH);
      float p3 = fexp2(acc[mi][ni][3] - SH);
      psum[ni] += (p0 + p1) + (p2 + p3);
      unsigned w0, w1;
      asm("v_cvt_pk_bf16_f32 %0, %1, %2" : "=v"(w0) : "v"(p0), "v"(p1));
      asm("v_cvt_pk_bf16_f32 %0, %1, %2" : "=v"(w1) : "v"(p2), "v"(p3));
      const int kv2 = (wr * 64 + mi * 16 + g * 4) * 2;
      *(uint2*)(smA + q_loc * 256 + (kv2 ^ ((q_loc & 15) << 4))) = (uint2){w0, w1};
    }
  }
#pragma unroll
  for (int ni = 0; ni < 4; ++ni) {
    float v = psum[ni];
    v += __shfl_xor(v, 16);
    v += __shfl_xor(v, 32);
    if (g == 0)
      atomicAdd(l + b * S_ + n_blk + wc * 64 + ni * 16 + c, v);
  }
  __syncthreads();                          // packed tile visible
  // coalesced store: wave wid covers q rows wid*32..+31; 4 rows x 256B / instr
#pragma unroll
  for (int i = 0; i < 8; ++i) {
    const int q_loc = wid * 32 + i * 4 + (lane >> 4);
    const int kvb = (lane & 15) * 16;
    uint4 v = *(const uint4*)(smA + q_loc * 256 + (kvb ^ ((q_loc & 15) << 4)));
    *(uint4*)((unsigned char*)Pb + (size_t)(n_blk + q_loc) * 4096 + m_blk * 2 + kvb) = v;
  }
}

// ---------------- stage 2b: O = (P V) / l, computed as O^T (R10 form) -------
// SWAPPED operands: A = Vs (d rows of V^T), B = P (q rows). 128x128 tile,
// 256 thr, 4 blocks/CU (inter-block overlap IS the pipeline — R14 lesson).
// m-major tile order: 4 d-blocks sharing a P q-panel adjacent (L2 reuse).
__global__ __launch_bounds__(256, 4) void k_pb(
    const unsigned short* __restrict__ P, const unsigned short* __restrict__ Vs,
    const float* __restrict__ l, float* __restrict__ out,
    int b_base, int bc) {
  __shared__ __align__(16) unsigned char smA[16384];
  __shared__ __align__(16) unsigned char smB[16384];
  const int lane = threadIdx.x & 63, wid = threadIdx.x >> 6;
  const int c = lane & 15, g = lane >> 4;
  const int wr = wid >> 1, wc = wid & 1;
  const int bloc = blockIdx.x % bc;
  const int tile = blockIdx.x / bc;         // 0..63
  const int b = b_base + bloc;
  const int m_blk = (tile & 3) * 128;       // d   (m-major: d tiles adjacent)
  const int n_blk = (tile >> 2) * 128;      // q
  const unsigned short* Pb = P + (size_t)bloc * S_ * S_;
  const unsigned char* Vsb = (const unsigned char*)(Vs + (size_t)b * 64 * 512 * 32);

  const int src_sw = ((lane & 7) * 16) ^ (((lane >> 3) & 7) << 4);
  // A = Vs d-rows: 128B LDS row = kv 0..63 = two 32-kv t-halves
  const unsigned char* ga = Vsb + (size_t)(src_sw >> 6) * 32768
      + (size_t)(m_blk + wid * 32 + (lane >> 3)) * 64 + (src_sw & 63);
  // B = P q-rows (row stride 4096B)
  const unsigned char* gb = (const unsigned char*)Pb
      + (size_t)(n_blk + wid * 32 + (lane >> 3)) * 4096;
  unsigned char* la = smA + wid * 4096;
  unsigned char* lb = smB + wid * 4096;

  f32x4 acc[4][4];
#pragma unroll
  for (int mi = 0; mi < 4; ++mi)
#pragma unroll
    for (int ni = 0; ni < 4; ++ni) acc[mi][ni] = (f32x4){0.f, 0.f, 0.f, 0.f};

  for (int step = 0; step < 32; ++step) {
    __syncthreads();
#pragma unroll
    for (int i = 0; i < 4; ++i) {
      gl_lds16(ga + (size_t)step * 65536 + i * 512, la + i * 1024);
      gl_lds16(gb + (size_t)i * 32768 + step * 128 + src_sw, lb + i * 1024);
    }
    __syncthreads();
#pragma unroll
    for (int kc = 0; kc < 2; ++kc) {
      const int ro = (kc * 64 + g * 16) ^ ((c & 7) << 4);
      short8 af[4], bf[4];
#pragma unroll
      for (int mi = 0; mi < 4; ++mi)
        af[mi] = *(const short8*)(smA + (wr * 64 + mi * 16 + c) * 128 + ro);
#pragma unroll
      for (int ni = 0; ni < 4; ++ni)
        bf[ni] = *(const short8*)(smB + (wc * 64 + ni * 16 + c) * 128 + ro);
#pragma unroll
      for (int mi = 0; mi < 4; ++mi)
#pragma unroll
        for (int ni = 0; ni < 4; ++ni)
          acc[mi][ni] = __builtin_amdgcn_mfma_f32_16x16x32_bf16(af[mi], bf[ni], acc[mi][ni], 0, 0, 0);
    }
  }

  const int m0 = m_blk + wr * 64;           // d
  const int n0 = n_blk + wc * 64;           // q
  float* ob = out + (size_t)b * S_ * D_;
#pragma unroll
  for (int ni = 0; ni < 4; ++ni) {
    const int q = n0 + ni * 16 + c;
    const float inv = 1.f / l[b * S_ + q];
#pragma unroll
    for (int mi = 0; mi < 4; ++mi) {
      float4 v;
      v.x = acc[mi][ni][0] * inv; v.y = acc[mi][ni][1] * inv;
      v.z = acc[mi][ni][2] * inv; v.w = acc[mi][ni][3] * inv;
      *(float4*)(ob + (size_t)q * D_ + m0 + mi * 16 + g * 4) = v;
    }
  }
}

// ---------------- launch ----------------------------------------------------
extern "C" void kernel_launch(void* const* d_in, const int* in_sizes, int n_in,
                              void* d_out, int out_size, void* d_ws, size_t ws_size,
                              hipStream_t stream) {
  const float* x  = (const float*)d_in[0];
  const float* Wq = (const float*)d_in[1];
  const float* bq = (const float*)d_in[2];
  const float* Wk = (const float*)d_in[3];
  const float* bk = (const float*)d_in[4];
  const float* Wv = (const float*)d_in[5];
  const float* bv = (const float*)d_in[6];
  float* out = (float*)d_out;

  // workspace layout (bf16 unless noted)
  unsigned short* xb = (unsigned short*)d_ws;              // [16384][512]  (dead after k_qkv)
  unsigned short* Wt = xb + (size_t)16384 * 512;           // [3][512][512] (dead after k_qkv)
  unsigned short* Qb = Wt + (size_t)3 * 512 * 512;         // [16384][512], pre-scaled
  unsigned short* Kb = Qb + (size_t)16384 * 512;           // [16384][512]
  unsigned short* Vs = Kb + (size_t)16384 * 512;           // [8][64][512][32] tile-major
  float* l = (float*)(Vs + (size_t)8 * 64 * 512 * 32);     // [8][2048] f32 — OWN slot
  unsigned short* Pfull = (unsigned short*)(l + 8 * 2048); // [8][2048][2048] (if ws allows)
  const size_t full_need =
      (size_t)((unsigned char*)(Pfull + (size_t)8 * 2048 * 2048) - (unsigned char*)d_ws);

  k_prep<<<dim3(7232), dim3(256), 0, stream>>>(x, Wq, Wk, Wv, xb, Wt, l);
  k_qkv<<<dim3(128, 4, 3), dim3(256), 0, stream>>>(xb, Wt, bq, bk, bv, Qb, Kb, Vs);

  if (ws_size >= full_need) {
    k_pa<<<dim3(2048), dim3(256), 0, stream>>>(Qb, Kb, Pfull, l, 0, 8);
    k_pb<<<dim3(512),  dim3(256), 0, stream>>>(Pfull, Vs, l, out, 0, 8);
  } else {
    // 2 batches of P fit exactly in the dead xb region (16.7 MB).
    unsigned short* P2 = xb;
    for (int g2 = 0; g2 < 4; ++g2) {
      k_pa<<<dim3(512), dim3(256), 0, stream>>>(Qb, Kb, P2, l, g2 * 2, 2);
      k_pb<<<dim3(128), dim3(256), 0, stream>>>(P2, Vs, l, out, g2 * 2, 2);
    }
  }
}